// Round 5
// baseline (60.164 us; speedup 1.0000x reference)
//
#include <hip/hip_runtime.h>

#define NPROLIF 12
#define NLIN 18
#define ROW 22                      // floats per element row
#define BLK 256                     // threads per block
#define NSLAB 8192                  // B*T/BLK

#define AS1 __attribute__((address_space(1)))
#define AS3 __attribute__((address_space(3)))

// branchless 4-way select (uniform index): v_cndmask chain on VALU
__device__ __forceinline__ float sel4(unsigned i, float x0, float x1, float x2, float x3) {
    float lo = (i & 1u) ? x1 : x0;
    float hi = (i & 1u) ? x3 : x2;
    return (i & 2u) ? hi : lo;
}

__global__ __launch_bounds__(BLK) void sindy_kernel(
    const float* __restrict__ cand,
    const float* __restrict__ a,
    const float* __restrict__ ss,
    const float* __restrict__ sgn,
    const float* __restrict__ K1p,
    const float* __restrict__ thetap,
    const float* __restrict__ K2p,
    const int* __restrict__ pidx,
    const int* __restrict__ lidx,
    const int* __restrict__ sprop,
    float* __restrict__ out)
{
    __shared__ float sRow[BLK*ROW];     // 22528 B, wave-private 5632 B slices

    const int tid  = threadIdx.x;
    const int wave = tid >> 6;
    const int lane = tid & 63;

    // ---- wave-private DMA staging: 7 issues, linear dest, fully coalesced ----
    const float* gw = cand + (size_t)blockIdx.x * (BLK*ROW) + wave * (64*ROW);
    float* lw = &sRow[wave * (64*ROW)];
    #pragma unroll
    for (int k = 0; k < 5; ++k)
        __builtin_amdgcn_global_load_lds((const AS1 void*)(gw + k*256 + lane*4),
                                         (AS3 void*)(lw + k*256), 16, 0, 0);
    #pragma unroll
    for (int j = 0; j < 2; ++j)
        __builtin_amdgcn_global_load_lds((const AS1 void*)(gw + 1280 + j*64 + lane),
                                         (AS3 void*)(lw + 1280 + j*64), 4, 0, 0);

    // wait ONLY this wave's 7 DMA loads; no barrier anywhere in the kernel
    asm volatile("s_waitcnt vmcnt(0)" ::: "memory");
    __builtin_amdgcn_sched_barrier(0);

    const float* row = &sRow[tid*ROW];   // [con, x0,x1,x2, prot0..17]
    float con = row[0], x0 = row[1], x1 = row[2], x2 = row[3];
    float xs  = x0 + x1 + x2;

    const float K1    = K1p[0];
    const float invTh = __builtin_amdgcn_rcpf(thetap[0]);   // theta=2 -> exact 0.5
    const float K2    = K2p[0];

    // masked coefficient, pure SALU: keep = sprop XOR signbit(a)  (zero-coef edge cases identical)
    auto coefFor = [&](int k) -> float {
        unsigned avb  = __float_as_uint(a[k]);              // s_load (uniform)
        unsigned keep = ((sprop[k] != 0) ? 1u : 0u) ^ (avb >> 31);
        return __uint_as_float(keep ? avb : 0u);            // s_cselect
    };

    float acc = coefFor(0) * con;

    #pragma unroll
    for (int t = 0; t < NPROLIF; ++t) {
        float coef = coefFor(1 + t);
        int ia = pidx[t*3+0], ib = pidx[t*3+1], ic = pidx[t*3+2];   // uniform s_loads
        float pA = sel4((unsigned)ia, x0, x1, x2, xs);
        float pB = sel4((unsigned)ib, x0, x1, x2, xs);
        float pC = row[4 + ic];                                     // LDS gather
        float h  = pC * __builtin_amdgcn_rcpf(K1 + pC);
        acc += coef * (pA * (1.0f - pB * invTh) * h);
    }

    #pragma unroll
    for (int t = 0; t < NLIN; ++t) {
        float coef = coefFor(1 + NPROLIF + t);
        int i0 = lidx[t*2+0], i1 = lidx[t*2+1];                     // uniform s_loads
        // A = 500*sign via sign-bit OR (SALU)
        float A   = __uint_as_float(0x43fa0000u /*500.0f*/ |
                                    (__float_as_uint(sgn[t]) & 0x80000000u));
        float ssv = ss[i1];                                          // uniform s_load
        float l0  = sel4((unsigned)i0, x0, x1, x2, xs);
        float pr  = row[4 + i1];                                     // LDS gather
        float dp  = pr - ssv;
        float adp = fabsf(dp);
        float h   = adp * __builtin_amdgcn_rcpf(K2 + adp);
        float e   = __expf(-(A * dp - 25.0f));                       // 500*(sign*dp-0.05)
        float sig = __builtin_amdgcn_rcpf(1.0f + e);
        acc += coef * (l0 * h * sig);
    }

    out[(size_t)blockIdx.x * BLK + tid] = acc;
}

extern "C" void kernel_launch(void* const* d_in, const int* in_sizes, int n_in,
                              void* d_out, int out_size, void* d_ws, size_t ws_size,
                              hipStream_t stream) {
    const float* cand = (const float*)d_in[0];
    const float* a    = (const float*)d_in[1];
    const float* ss   = (const float*)d_in[2];
    const float* sgn  = (const float*)d_in[3];
    const float* K1   = (const float*)d_in[4];
    const float* th   = (const float*)d_in[5];
    const float* K2   = (const float*)d_in[6];
    const int*   pidx = (const int*)d_in[7];
    const int*   lidx = (const int*)d_in[8];
    const int*   sp   = (const int*)d_in[9];
    float* out = (float*)d_out;

    hipLaunchKernelGGL(sindy_kernel, dim3(NSLAB), dim3(BLK), 0, stream,
                       cand, a, ss, sgn, K1, th, K2, pidx, lidx, sp, out);
}

// Round 6
// 44.547 us; speedup vs baseline: 1.3506x; 1.3506x over previous
//
#include <hip/hip_runtime.h>

#define NPROLIF 12
#define NLIN 18
#define ROW 22                    // floats per element row
#define BLK 256                   // threads per block
#define F4_PER_BLK (BLK*ROW/4)    // 1408 float4 per block slab
#define NSLAB 8192                // B*T/BLK

#define AS1 __attribute__((address_space(1)))
#define AS3 __attribute__((address_space(3)))

// branchless 4-way select, index is wave-uniform; 3 v_cndmask on the VALU pipe
__device__ __forceinline__ float sel4(unsigned i, float x0, float x1, float x2, float x3) {
    float lo = (i & 1u) ? x1 : x0;
    float hi = (i & 1u) ? x3 : x2;
    return (i & 2u) ? hi : lo;
}

__global__ __launch_bounds__(BLK) void sindy_kernel(
    const float* __restrict__ cand,
    const float* __restrict__ a,
    const float* __restrict__ ss,
    const float* __restrict__ sgn,
    const float* __restrict__ K1p,
    const float* __restrict__ thetap,
    const float* __restrict__ K2p,
    const int* __restrict__ pidx,
    const int* __restrict__ lidx,
    const int* __restrict__ sprop,
    float* __restrict__ out)
{
    __shared__ float sRow[BLK*ROW];   // 22528 B: raw 22-float rows, linear (global_load_lds dest)
    __shared__ uint2 sPP[NPROLIF];    // {bits[1:0]=ia, [3:2]=ib, [15:8]=prot byte off; masked coef}
    __shared__ uint4 sLP[NLIN];       // {bits[1:0]=i0, [15:8]=prot byte off; masked coef; 500*sign; ss[i1]}
    __shared__ float sScal[4];        // K1, 1/theta, K2, coef0

    const int tid = threadIdx.x;
    const int wbase = tid & ~63;      // lane-0 tid of this wave (wave-uniform LDS base)

    // ---- XCD-contiguous slab remap: blocks round-robin XCDs (bid%8 = XCD),
    //      give each XCD a contiguous 1/8 of the input (23 MB region per L2).
    const int slab = ((blockIdx.x & 7) << 10) | (blockIdx.x >> 3);   // bijective, NSLAB=8192

    // ---- kick off global->LDS DMA staging first (width-16 direct loads) ----
    const float4* g4 = reinterpret_cast<const float4*>(cand)
                       + (long long)slab * F4_PER_BLK;
    float4* s4 = reinterpret_cast<float4*>(sRow);
    #pragma unroll
    for (int k = 0; k < 5; ++k) {
        __builtin_amdgcn_global_load_lds(
            (const AS1 void*)(g4 + k*BLK + tid),
            (AS3 void*)(s4 + k*BLK + wbase), 16, 0, 0);
    }
    if (tid < F4_PER_BLK - 5*BLK) {   // last 128 float4s
        __builtin_amdgcn_global_load_lds(
            (const AS1 void*)(g4 + 5*BLK + tid),
            (AS3 void*)(s4 + 5*BLK + wbase), 16, 0, 0);
    }

    // ---- per-block constant build (overlaps the DMA) ----
    if (tid < NPROLIF) {
        int i = tid;
        int ia = pidx[i*3+0], ib = pidx[i*3+1], ic = pidx[i*3+2];
        float av = a[1+i];
        bool keep = sprop[1+i] ? (av >= 0.f) : (av <= 0.f);
        unsigned offs = (unsigned)ia | ((unsigned)ib << 2) | ((unsigned)(16 + ic*4) << 8);
        sPP[i] = make_uint2(offs, __float_as_uint(keep ? av : 0.f));
    } else if (tid < NPROLIF + NLIN) {           // tids 12..29
        int j = tid - NPROLIF;
        int i0 = lidx[j*2+0], i1 = lidx[j*2+1];
        float av = a[1+NPROLIF+j];
        bool keep = sprop[1+NPROLIF+j] ? (av >= 0.f) : (av <= 0.f);
        unsigned offs = (unsigned)i0 | ((unsigned)(16 + i1*4) << 8);
        sLP[j] = make_uint4(offs,
                            __float_as_uint(keep ? av : 0.f),
                            __float_as_uint(500.f * sgn[j]),
                            __float_as_uint(ss[i1]));
    } else if (tid == NPROLIF + NLIN) {          // tid 30
        float av = a[0];
        bool keep = sprop[0] ? (av >= 0.f) : (av <= 0.f);
        sScal[0] = K1p[0];
        sScal[1] = 1.0f / thetap[0];
        sScal[2] = K2p[0];
        sScal[3] = keep ? av : 0.f;
    }

    __syncthreads();   // drains vmcnt (DMA) + lgkmcnt

    // ---- header: con, x0..x2 ----
    const char* row = (const char*)&sRow[tid*ROW];   // [con, x0,x1,x2, prot0..17]
    float con = sRow[tid*ROW+0];
    float x0  = sRow[tid*ROW+1];
    float x1  = sRow[tid*ROW+2];
    float x2  = sRow[tid*ROW+3];
    float xs  = x0 + x1 + x2;

    const float K1 = sScal[0], invTh = sScal[1], K2 = sScal[2];
    float acc = sScal[3] * con;                      // con term

    #pragma unroll
    for (int i = 0; i < NPROLIF; ++i) {
        uint2 pp = sPP[i];
        float coef = __uint_as_float(pp.y);
        float pA = sel4(pp.x & 3u, x0, x1, x2, xs);
        float pB = sel4((pp.x >> 2) & 3u, x0, x1, x2, xs);
        float pC = *(const float*)(row + ((pp.x >> 8) & 0xffu));   // LDS gather
        float h  = pC * __builtin_amdgcn_rcpf(K1 + pC);
        acc += coef * (pA * (1.0f - pB * invTh) * h);
    }

    #pragma unroll
    for (int j = 0; j < NLIN; ++j) {
        uint4 lp = sLP[j];
        float coef = __uint_as_float(lp.y);
        float A    = __uint_as_float(lp.z);          // 500*sign
        float ssv  = __uint_as_float(lp.w);
        float l0 = sel4(lp.x & 3u, x0, x1, x2, xs);
        float pr = *(const float*)(row + ((lp.x >> 8) & 0xffu));   // LDS gather
        float dp  = pr - ssv;
        float adp = fabsf(dp);
        float h   = adp * __builtin_amdgcn_rcpf(K2 + adp);
        float z   = A * dp - 25.0f;                  // 500*(sign*dp - 0.05)
        float e   = __expf(-z);
        float sig = __builtin_amdgcn_rcpf(1.0f + e);
        acc += coef * (l0 * h * sig);
    }

    out[(long long)slab * BLK + tid] = acc;
}

extern "C" void kernel_launch(void* const* d_in, const int* in_sizes, int n_in,
                              void* d_out, int out_size, void* d_ws, size_t ws_size,
                              hipStream_t stream) {
    const float* cand = (const float*)d_in[0];
    const float* a    = (const float*)d_in[1];
    const float* ss   = (const float*)d_in[2];
    const float* sgn  = (const float*)d_in[3];
    const float* K1   = (const float*)d_in[4];
    const float* th   = (const float*)d_in[5];
    const float* K2   = (const float*)d_in[6];
    const int*   pidx = (const int*)d_in[7];
    const int*   lidx = (const int*)d_in[8];
    const int*   sp   = (const int*)d_in[9];
    float* out = (float*)d_out;

    hipLaunchKernelGGL(sindy_kernel, dim3(NSLAB), dim3(BLK), 0, stream,
                       cand, a, ss, sgn, K1, th, K2, pidx, lidx, sp, out);
}